// Round 12
// baseline (113.807 us; speedup 1.0000x reference)
//
#include <hip/hip_runtime.h>
#include <math.h>

#define KM 192
#define EPSF 1e-6f
#define QMIN 0.5f
#define BT 512               // threads per block (8 waves)
#define TPE 64               // tiles (blocks) per event -> grid = 256 = 1/CU

__device__ __forceinline__ float clipb(float b) {
    return fminf(fmaxf(b, 1e-4f), 1.0f - 1e-4f);
}
// atanh(b) = 0.5*ln((1+b)/(1-b)); b in [1e-4, 1-1e-4]
__device__ __forceinline__ float fast_atanh(float b) {
    float r = (1.f + b) * __builtin_amdgcn_rcpf(1.f - b);
    return 0.34657359f * __builtin_amdgcn_logf(r);
}
__device__ __forceinline__ float bcast(float v, int j) {
    return __int_as_float(__builtin_amdgcn_readlane(__float_as_int(v), j));
}
__device__ __forceinline__ unsigned long long aload64(const unsigned long long* p) {
    return __hip_atomic_load(p, __ATOMIC_RELAXED, __HIP_MEMORY_SCOPE_AGENT);
}
__device__ __forceinline__ float aloadf(const float* p) {
    return __hip_atomic_load(p, __ATOMIC_RELAXED, __HIP_MEMORY_SCOPE_AGENT);
}

// ---- single fused kernel: 256 blocks x 512 threads, 1 block/CU ----
// Phase A: per-block LDS argmax/energy partials over grid-stride hits -> global
//          atomics. Device barrier (all blocks resident by construction).
// Phase B: alpha rebuild per block, object-owner readlane rep loop.
// Last-done block finalizes.
// pack = (bits(clip(beta)) << 32) | (N-1-i): beta>0 -> bits monotone; low word
// reproduces jnp.argmax first-index tiebreak. argmax(beta) == argmax(q).
__global__ void __launch_bounds__(BT, 2)
k_fused(const float* __restrict__ beta, const float* __restrict__ cc,
        const float* __restrict__ pe,   const float* __restrict__ te,
        const int* __restrict__ tidx,
        unsigned long long* __restrict__ packs,
        float* __restrict__ enm, float* __restrict__ eden,
        float* __restrict__ scal, unsigned int* __restrict__ cnt,
        float* __restrict__ out, int N) {
    const int e    = blockIdx.x & 3;
    const int tile = blockIdx.x >> 2;
    const int tid  = threadIdx.x;
    const int lane = tid & 63;
    const int wv   = tid >> 6;
    const int NBLK = gridDim.x;
    const size_t base = (size_t)e * N;
    const int STRIDE = TPE * BT;

    __shared__ unsigned long long smax[KM];
    __shared__ float sn[KM], sd[KM];
    __shared__ float4 sa[KM];
    __shared__ float sw[24];
    __shared__ int lastFlag;

    if (tid < KM) { smax[tid] = 0ull; sn[tid] = 0.f; sd[tid] = 0.f; }
    __syncthreads();

    // ---------- Phase A ----------
    float bn = 0.f, cn = 0.f;
    for (int s = 0; tile * BT + s * STRIDE < N; ++s) {
        int i = tile * BT + s * STRIDE + tid;
        if (i < N) {
            int   t  = tidx[base + i];
            float bc = clipb(beta[base + i]);
            if (t > 0) {
                unsigned long long pack =
                    ((unsigned long long)__float_as_uint(bc) << 32) |
                    (unsigned long long)(unsigned)(N - 1 - i);
                atomicMax(&smax[t], pack);
                float tev = te[base + i];
                float edv = (pe[base + i] - tev) * __builtin_amdgcn_rcpf(tev + 1.f);
                float ad  = fabsf(edv);
                float eh  = (ad <= 2.f) ? 0.5f * ad * ad : 2.f * (ad - 1.f);
                atomicAdd(&sn[t], bc * eh);
                atomicAdd(&sd[t], bc);
            } else { bn += bc; cn += 1.f; }
        }
    }
    __syncthreads();
    if (tid < KM) {
        unsigned long long v = smax[tid];
        if (v) atomicMax(&packs[e * KM + tid], v);
        float vd = sd[tid];
        if (vd != 0.f) {
            atomicAdd(&enm [e * KM + tid], sn[tid]);
            atomicAdd(&eden[e * KM + tid], vd);
        }
    }
    for (int off = 32; off > 0; off >>= 1) {
        bn += __shfl_down(bn, off);
        cn += __shfl_down(cn, off);
    }
    if (lane == 0) { sw[wv] = bn; sw[8 + wv] = cn; }
    __syncthreads();
    if (tid == 0) {
        float b2 = 0.f, c2 = 0.f;
        #pragma unroll
        for (int w = 0; w < 8; ++w) { b2 += sw[w]; c2 += sw[8 + w]; }
        atomicAdd(&scal[e * 8 + 3], b2);
        atomicAdd(&scal[e * 8 + 4], c2);
    }

    // ---------- device barrier (all 256 blocks resident: 8 waves/block) ----------
    if (tid == 0) {
        __threadfence();
        __hip_atomic_fetch_add(&cnt[0], 1u, __ATOMIC_ACQ_REL, __HIP_MEMORY_SCOPE_AGENT);
        while (__hip_atomic_load(&cnt[0], __ATOMIC_ACQUIRE, __HIP_MEMORY_SCOPE_AGENT)
               < (unsigned)NBLK) { __builtin_amdgcn_s_sleep(1); }
    }
    __syncthreads();

    // ---------- Phase B ----------
    if (tid < KM) {
        unsigned long long v = aload64(&packs[e * KM + tid]);
        float4 a = make_float4(0.f, 0.f, 0.f, 0.f);
        if (v) {
            int idx  = N - 1 - (int)(unsigned)(v & 0xffffffffull);
            float bw = __uint_as_float((unsigned)(v >> 32));
            float at = fast_atanh(bw);
            float2 cp = ((const float2*)cc)[base + idx];
            a = make_float4(cp.x, cp.y, fmaf(at, at, QMIN), bw);
        }
        sa[tid] = a;
    }
    __syncthreads();

    const float4 o0 = sa[lane];          // my 3 objects in registers
    const float4 o1 = sa[lane + 64];
    const float4 o2 = sa[lane + 128];

    float r0 = 0.f, r1 = 0.f, r2 = 0.f, lvh = 0.f;
    for (int s = 0; tile * BT + wv * 64 + s * STRIDE < N; ++s) {
        const int i = tile * BT + wv * 64 + s * STRIDE + lane;
        const bool ok = i < N;
        const size_t ii = base + (ok ? i : 0);
        const float2 cp = ((const float2*)cc)[ii];
        const float  bc = clipb(beta[ii]);
        const int    t  = ok ? tidx[ii] : 0;
        const float  at = fast_atanh(bc);
        const float  qh = ok ? fmaf(at, at, QMIN) : 0.f;   // 0 kills pad hits

        if (t > 0) {                     // member: att + own-hinge correction
            float4 av = sa[t];
            float dx = cp.x - av.x, dy = cp.y - av.y;
            float d2 = fmaf(dx, dx, dy * dy);
            float hin = fmaxf(1.f - __builtin_amdgcn_sqrtf(d2 + EPSF), 0.f);
            lvh = fmaf(qh * av.z, d2 - hin, lvh);
        }
        // rep separability: sum_i q_i sum_k hinge*q_k = sum_k q_k (sum_i q_i*hinge)
        #pragma unroll 16
        for (int j = 0; j < 64; ++j) {
            const float xh = bcast(cp.x, j);
            const float yh = bcast(cp.y, j);
            const float qb = bcast(qh,  j);
            float dx0 = o0.x - xh, dy0 = o0.y - yh;
            float dx1 = o1.x - xh, dy1 = o1.y - yh;
            float dx2 = o2.x - xh, dy2 = o2.y - yh;
            float d0 = fmaf(dx0, dx0, fmaf(dy0, dy0, EPSF));
            float d1 = fmaf(dx1, dx1, fmaf(dy1, dy1, EPSF));
            float d2 = fmaf(dx2, dx2, fmaf(dy2, dy2, EPSF));
            r0 = fmaf(fmaxf(1.f - __builtin_amdgcn_sqrtf(d0), 0.f), qb, r0);
            r1 = fmaf(fmaxf(1.f - __builtin_amdgcn_sqrtf(d1), 0.f), qb, r1);
            r2 = fmaf(fmaxf(1.f - __builtin_amdgcn_sqrtf(d2), 0.f), qb, r2);
        }
    }
    float lv = fmaf(o0.z, r0, fmaf(o1.z, r1, fmaf(o2.z, r2, lvh)));
    for (int off = 32; off > 0; off >>= 1) lv += __shfl_down(lv, off);
    if (lane == 0) sw[wv] = lv;
    __syncthreads();
    if (tid == 0) {
        float a = 0.f;
        #pragma unroll
        for (int w = 0; w < 8; ++w) a += sw[w];
        atomicAdd(&scal[e * 8 + 0], a);
    }

    // ---------- last-block finalize ----------
    if (tid == 0) {
        __threadfence();
        unsigned int old = __hip_atomic_fetch_add(&cnt[1], 1u, __ATOMIC_ACQ_REL,
                                                  __HIP_MEMORY_SCOPE_AGENT);
        lastFlag = (old == (unsigned)NBLK - 1u);
    }
    __syncthreads();
    if (!lastFlag) return;
    __threadfence();

    float tot = 0.f;
    for (int ev = 0; ev < 4; ++ev) {
        float lb = 0.f, nv = 0.f, le = 0.f;
        if (tid < KM) {
            unsigned long long v = aload64(&packs[ev * KM + tid]);
            if (v) {
                lb = 1.f - __uint_as_float((unsigned)(v >> 32));
                nv = 1.f;
                le = aloadf(&enm[ev * KM + tid]) /
                     (aloadf(&eden[ev * KM + tid]) + EPSF);
            }
        }
        for (int off = 32; off > 0; off >>= 1) {
            lb += __shfl_down(lb, off);
            nv += __shfl_down(nv, off);
            le += __shfl_down(le, off);
        }
        if (lane == 0) { sw[wv] = lb; sw[8 + wv] = nv; sw[16 + wv] = le; }
        __syncthreads();
        if (tid == 0) {
            float lbs = 0.f, nvs = 0.f, les = 0.f;
            #pragma unroll
            for (int w = 0; w < 8; ++w) { lbs += sw[w]; nvs += sw[8 + w]; les += sw[16 + w]; }
            float nobj = nvs + EPSF;
            tot += aloadf(&scal[ev * 8 + 0]) / (float)N + lbs / nobj
                 + aloadf(&scal[ev * 8 + 3]) / (aloadf(&scal[ev * 8 + 4]) + EPSF)
                 + les / nobj;
        }
        __syncthreads();
    }
    if (tid == 0) out[0] = tot * 0.25f;
}

extern "C" void kernel_launch(void* const* d_in, const int* in_sizes, int n_in,
                              void* d_out, int out_size, void* d_ws, size_t ws_size,
                              hipStream_t stream) {
    const int B = 4;
    const int N = in_sizes[0] / B;               // beta is [B,N,1]

    const float* beta = (const float*)d_in[0];
    const float* cc   = (const float*)d_in[1];
    const float* pe   = (const float*)d_in[2];
    const float* te   = (const float*)d_in[3];
    const int*   tidx = (const int*)  d_in[4];
    float* out = (float*)d_out;

    // ws: packs u64[B*KM] | enm f32[B*KM] | eden f32[B*KM] | scal f32[B*8] | cnt u32[16]
    char* ws = (char*)d_ws;
    unsigned long long* packs = (unsigned long long*)ws;
    float* enm  = (float*)(ws + (size_t)B * KM * 8);
    float* eden = enm  + B * KM;
    float* scal = eden + B * KM;
    unsigned int* cnt = (unsigned int*)(scal + B * 8);
    const size_t zeroBytes = (char*)(cnt + 16) - ws;   // ~12.6 KB

    (void)hipMemsetAsync(d_ws, 0, zeroBytes, stream);
    k_fused<<<dim3(TPE * B), dim3(BT), 0, stream>>>(
        beta, cc, pe, te, tidx, packs, enm, eden, scal, cnt, out, N);
}

// Round 13
// 104.544 us; speedup vs baseline: 1.0886x; 1.0886x over previous
//
#include <hip/hip_runtime.h>
#include <math.h>

#define KM 192
#define EPSF 1e-6f
#define QMIN 0.5f
#define BLK 256
#define HA 4
#define TILEA (BLK * HA)     // 1024 hits per k_pre tile

__device__ __forceinline__ float clipb(float b) {
    return fminf(fmaxf(b, 1e-4f), 1.0f - 1e-4f);
}
// atanh(b) = 0.5*ln((1+b)/(1-b)); b in [1e-4, 1-1e-4]
__device__ __forceinline__ float fast_atanh(float b) {
    float r = (1.f + b) * __builtin_amdgcn_rcpf(1.f - b);
    return 0.34657359f * __builtin_amdgcn_logf(r);
}
__device__ __forceinline__ float bcast(float v, int j) {
    return __int_as_float(__builtin_amdgcn_readlane(__float_as_int(v), j));
}

// ---- K1: per-block partials, PLAIN stores only (no global RMW) ----
// pack = (bits(clip(beta)) << 32) | (N-1-i): beta>0 -> bits monotone; low word
// reproduces jnp.argmax first-index tiebreak. argmax(beta) == argmax(q).
__global__ void __launch_bounds__(BLK)
k_pre(const float* __restrict__ beta, const int* __restrict__ tidx,
      const float* __restrict__ pe,   const float* __restrict__ te,
      unsigned long long* __restrict__ pm, float* __restrict__ pn,
      float* __restrict__ pd, float* __restrict__ pb, int N, int HBT) {
    const int e = blockIdx.y, tile = blockIdx.x, tid = threadIdx.x;
    __shared__ unsigned long long smax[KM];
    __shared__ float sn[KM], sd[KM];
    __shared__ float sw[8];
    if (tid < KM) { smax[tid] = 0ull; sn[tid] = 0.f; sd[tid] = 0.f; }
    __syncthreads();

    const size_t base = (size_t)e * N;
    float bn = 0.f, cn = 0.f;
    #pragma unroll
    for (int h = 0; h < HA; ++h) {
        int i = tile * TILEA + h * BLK + tid;
        if (i < N) {
            int   t  = tidx[base + i];
            float bc = clipb(beta[base + i]);
            if (t > 0) {
                unsigned long long pack =
                    ((unsigned long long)__float_as_uint(bc) << 32) |
                    (unsigned long long)(unsigned)(N - 1 - i);
                atomicMax(&smax[t], pack);                    // LDS atomic (cheap)
                float tev = te[base + i];
                float edv = (pe[base + i] - tev) * __builtin_amdgcn_rcpf(tev + 1.f);
                float ad  = fabsf(edv);
                float eh  = (ad <= 2.f) ? 0.5f * ad * ad : 2.f * (ad - 1.f);
                atomicAdd(&sn[t], bc * eh);
                atomicAdd(&sd[t], bc);
            } else { bn += bc; cn += 1.f; }
        }
    }
    __syncthreads();

    const size_t row = (size_t)(e * HBT + tile) * KM;
    if (tid < KM) {                                           // plain coalesced stores
        pm[row + tid] = smax[tid];
        pn[row + tid] = sn[tid];
        pd[row + tid] = sd[tid];
    }
    for (int off = 32; off > 0; off >>= 1) {
        bn += __shfl_down(bn, off);
        cn += __shfl_down(cn, off);
    }
    const int wv = tid >> 6;
    if ((tid & 63) == 0) { sw[wv] = bn; sw[4 + wv] = cn; }
    __syncthreads();
    if (tid == 0) {
        pb[(size_t)(e * HBT + tile) * 2 + 0] = (sw[0] + sw[1]) + (sw[2] + sw[3]);
        pb[(size_t)(e * HBT + tile) * 2 + 1] = (sw[4] + sw[5]) + (sw[6] + sw[7]);
    }
}

// ---- K2: reduce partials -> alpha table + per-event constant part
//      cpart = L_beta + L_noise + L_E. Also zeroes cnt. 4 blocks. ----
__global__ void __launch_bounds__(BLK)
k_red(const unsigned long long* __restrict__ pm, const float* __restrict__ pn,
      const float* __restrict__ pd, const float* __restrict__ pb,
      const float* __restrict__ cc, float4* __restrict__ alpha,
      float* __restrict__ cpart, unsigned int* __restrict__ cnt, int N, int HBT) {
    const int e = blockIdx.x, tid = threadIdx.x;
    __shared__ float sred[20];
    float lb = 0.f, nv = 0.f, le = 0.f;
    if (tid < KM) {
        unsigned long long v = 0ull;
        float ns = 0.f, ds = 0.f;
        for (int t = 0; t < HBT; ++t) {
            size_t o = (size_t)(e * HBT + t) * KM + tid;
            unsigned long long p = pm[o];
            if (p > v) v = p;
            ns += pn[o]; ds += pd[o];
        }
        float4 a = make_float4(0.f, 0.f, 0.f, 0.f);
        if (v) {
            int idx  = N - 1 - (int)(unsigned)(v & 0xffffffffull);
            float bw = __uint_as_float((unsigned)(v >> 32));  // clipped beta_alpha
            float at = fast_atanh(bw);
            float2 cp = ((const float2*)cc)[(size_t)e * N + idx];
            a = make_float4(cp.x, cp.y, fmaf(at, at, QMIN), bw);
            lb = 1.f - bw; nv = 1.f; le = ns / (ds + EPSF);
        }
        alpha[e * KM + tid] = a;
    }
    float bn = 0.f, cn = 0.f;
    for (int t = tid; t < HBT; t += BLK) {
        bn += pb[(size_t)(e * HBT + t) * 2 + 0];
        cn += pb[(size_t)(e * HBT + t) * 2 + 1];
    }
    for (int off = 32; off > 0; off >>= 1) {
        lb += __shfl_down(lb, off);
        nv += __shfl_down(nv, off);
        le += __shfl_down(le, off);
        bn += __shfl_down(bn, off);
        cn += __shfl_down(cn, off);
    }
    const int wv = tid >> 6;
    if ((tid & 63) == 0) {
        sred[wv] = lb; sred[4 + wv] = nv; sred[8 + wv] = le;
        sred[12 + wv] = bn; sred[16 + wv] = cn;
    }
    __syncthreads();
    if (tid == 0) {
        float lbs = 0.f, nvs = 0.f, les = 0.f, bns = 0.f, cns = 0.f;
        #pragma unroll
        for (int w = 0; w < 4; ++w) {
            lbs += sred[w]; nvs += sred[4 + w]; les += sred[8 + w];
            bns += sred[12 + w]; cns += sred[16 + w];
        }
        float nobj = nvs + EPSF;
        cpart[e] = lbs / nobj + bns / (cns + EPSF) + les / nobj;
        if (e == 0) cnt[0] = 0u;
    }
}

// ---- K3: lean L_V sweep (object-owner readlane loop) + last-block finalize ----
__global__ void __launch_bounds__(BLK)
k_main(const float* __restrict__ beta, const float* __restrict__ cc,
       const int* __restrict__ tidx,  const float4* __restrict__ alpha,
       const float* __restrict__ cpart, float* __restrict__ lvp,
       unsigned int* __restrict__ cnt, float* __restrict__ out,
       int N, int MB2) {
    const int e = blockIdx.y, tile = blockIdx.x, tid = threadIdx.x;
    const int lane = tid & 63, wv = tid >> 6;
    __shared__ float4 sa[KM];
    __shared__ float sw[16];
    __shared__ int lastFlag;
    if (tid < KM) sa[tid] = alpha[e * KM + tid];   // coalesced, L2-hot (3KB)
    __syncthreads();

    const float4 o0 = sa[lane];                    // my 3 objects in registers
    const float4 o1 = sa[lane + 64];
    const float4 o2 = sa[lane + 128];

    const size_t base = (size_t)e * N;
    const int i = tile * BLK + wv * 64 + lane;
    const bool ok = i < N;
    const size_t ii = base + (ok ? i : 0);
    const float2 cp = ((const float2*)cc)[ii];
    const float  bc = clipb(beta[ii]);
    const int    t  = ok ? tidx[ii] : 0;
    const float  at = fast_atanh(bc);
    const float  qh = ok ? fmaf(at, at, QMIN) : 0.f;   // 0 kills pad hits

    float lvh = 0.f;
    if (t > 0) {                                   // member: att + own-hinge corr.
        float4 av = sa[t];
        float dx = cp.x - av.x, dy = cp.y - av.y;
        float d2 = fmaf(dx, dx, dy * dy);
        float hin = fmaxf(1.f - __builtin_amdgcn_sqrtf(d2 + EPSF), 0.f);
        lvh = qh * av.z * (d2 - hin);
    }

    // rep separability: sum_i q_i sum_k hinge*q_k = sum_k q_k (sum_i q_i*hinge)
    float r0 = 0.f, r1 = 0.f, r2 = 0.f;
    #pragma unroll 8
    for (int j = 0; j < 64; ++j) {
        const float xh = bcast(cp.x, j);
        const float yh = bcast(cp.y, j);
        const float qb = bcast(qh,  j);
        float dx0 = o0.x - xh, dy0 = o0.y - yh;
        float dx1 = o1.x - xh, dy1 = o1.y - yh;
        float dx2 = o2.x - xh, dy2 = o2.y - yh;
        float d0 = fmaf(dx0, dx0, fmaf(dy0, dy0, EPSF));
        float d1 = fmaf(dx1, dx1, fmaf(dy1, dy1, EPSF));
        float d2 = fmaf(dx2, dx2, fmaf(dy2, dy2, EPSF));
        r0 = fmaf(fmaxf(1.f - __builtin_amdgcn_sqrtf(d0), 0.f), qb, r0);
        r1 = fmaf(fmaxf(1.f - __builtin_amdgcn_sqrtf(d1), 0.f), qb, r1);
        r2 = fmaf(fmaxf(1.f - __builtin_amdgcn_sqrtf(d2), 0.f), qb, r2);
    }
    float lv = fmaf(o0.z, r0, fmaf(o1.z, r1, fmaf(o2.z, r2, lvh)));

    for (int off = 32; off > 0; off >>= 1) lv += __shfl_down(lv, off);
    if (lane == 0) sw[wv] = lv;
    __syncthreads();
    if (tid == 0)
        lvp[e * MB2 + tile] = (sw[0] + sw[1]) + (sw[2] + sw[3]);  // plain store

    // ---- last-block-done finalize ----
    if (tid == 0) {
        __threadfence();                                          // release lvp
        unsigned int old = atomicAdd(&cnt[0], 1u);
        lastFlag = (old == gridDim.x * gridDim.y - 1u);
    }
    __syncthreads();
    if (!lastFlag) return;
    __threadfence();                                              // acquire

    float s = 0.f;
    for (int idx = tid; idx < 4 * MB2; idx += BLK) s += lvp[idx];
    float c = (tid < 4) ? cpart[tid] : 0.f;
    for (int off = 32; off > 0; off >>= 1) {
        s += __shfl_down(s, off);
        c += __shfl_down(c, off);
    }
    if (lane == 0) { sw[wv] = s; sw[8 + wv] = c; }
    __syncthreads();
    if (tid == 0) {
        float ssum = (sw[0] + sw[1]) + (sw[2] + sw[3]);
        float csum = (sw[8] + sw[9]) + (sw[10] + sw[11]);
        out[0] = ssum / (4.f * (float)N) + csum * 0.25f;
    }
}

extern "C" void kernel_launch(void* const* d_in, const int* in_sizes, int n_in,
                              void* d_out, int out_size, void* d_ws, size_t ws_size,
                              hipStream_t stream) {
    const int B = 4;
    const int N = in_sizes[0] / B;               // beta is [B,N,1]
    const int HBT = (N + TILEA - 1) / TILEA;     // k_pre tiles (49)
    const int MB2 = (N + BLK - 1) / BLK;         // k_main tiles (196)

    const float* beta = (const float*)d_in[0];
    const float* cc   = (const float*)d_in[1];
    const float* pe   = (const float*)d_in[2];
    const float* te   = (const float*)d_in[3];
    const int*   tidx = (const int*)  d_in[4];
    float* out = (float*)d_out;

    // ws (no memset needed; every word rewritten each call):
    // pm u64[B*HBT*KM] | pn f32[...] | pd f32[...] | pb f32[B*HBT*2]
    // | alpha float4[B*KM] (16B-aligned) | cpart f32[4] | lvp f32[B*MB2] | cnt u32
    char* ws = (char*)d_ws;
    unsigned long long* pm = (unsigned long long*)ws;
    float* pn = (float*)(ws + (size_t)B * HBT * KM * 8);
    float* pd = pn + (size_t)B * HBT * KM;
    float* pb = pd + (size_t)B * HBT * KM;
    size_t off = (size_t)B * HBT * KM * 16 + (size_t)B * HBT * 2 * 4;
    off = (off + 15) & ~(size_t)15;              // align alpha to 16B
    float4* alpha = (float4*)(ws + off);
    float* cpart = (float*)(alpha + B * KM);
    float* lvp   = cpart + 4;
    unsigned int* cnt = (unsigned int*)(lvp + B * MB2);

    k_pre<<<dim3(HBT, B), dim3(BLK), 0, stream>>>(beta, tidx, pe, te, pm, pn, pd, pb, N, HBT);
    k_red<<<dim3(B), dim3(BLK), 0, stream>>>(pm, pn, pd, pb, cc, alpha, cpart, cnt, N, HBT);
    k_main<<<dim3(MB2, B), dim3(BLK), 0, stream>>>(
        beta, cc, tidx, alpha, cpart, lvp, cnt, out, N, MB2);
}